// Round 8
// baseline (1009.301 us; speedup 1.0000x reference)
//
#include <hip/hip_runtime.h>
#include <hip/hip_bf16.h>
#include <math.h>

// bf16 MFMA fragment type: gfx950 builtins take <8 x __bf16>.
typedef __attribute__((ext_vector_type(8))) __bf16 frag8;
typedef __attribute__((ext_vector_type(4))) float floatx4;

__device__ __forceinline__ void gload_lds16(const void* g, void* l) {
  __builtin_amdgcn_global_load_lds((__attribute__((address_space(1))) void*)g,
                                   (__attribute__((address_space(3))) void*)l,
                                   16, 0, 0);
}

// q is an exact small integer in fp32 -> low 16 bits are zero -> truncate.
__device__ __forceinline__ unsigned short f32_bits_bf16(float f) {
  return (unsigned short)(__float_as_uint(f) >> 16);
}

// ---------------------------------------------------------------------------
// Per-row symmetric int8 fake-quant: src fp32 [rows, C] -> q (bf16 bits) + scale.
// C = NITER * 1024, 256 threads/block, one block per row, fully unrolled.
// ---------------------------------------------------------------------------
template<int NITER>
__global__ void quant_rows_kernel(const float* __restrict__ src,
                                  unsigned short* __restrict__ dst,
                                  float* __restrict__ scales,
                                  int C) {
  const int row = blockIdx.x;
  const int t = threadIdx.x;
  const float4* s4 = (const float4*)(src + (size_t)row * C);
  float4 v[NITER];
  float amax = 0.0f;
#pragma unroll
  for (int i = 0; i < NITER; ++i) {
    v[i] = s4[t + (i << 8)];
    amax = fmaxf(amax, fmaxf(fmaxf(fabsf(v[i].x), fabsf(v[i].y)),
                             fmaxf(fabsf(v[i].z), fabsf(v[i].w))));
  }
#pragma unroll
  for (int off = 32; off > 0; off >>= 1)
    amax = fmaxf(amax, __shfl_xor(amax, off));
  __shared__ float red[4];
  if ((t & 63) == 0) red[t >> 6] = amax;
  __syncthreads();
  if (t == 0) {
    float m = fmaxf(fmaxf(red[0], red[1]), fmaxf(red[2], red[3]));
    float s = fmaxf(m * (1.0f / 127.0f), 1e-8f);
    red[0] = s;
    scales[row] = s;
  }
  __syncthreads();
  const float scale = red[0];
  ushort4* o4 = (ushort4*)(dst + (size_t)row * C);
#pragma unroll
  for (int i = 0; i < NITER; ++i) {
    ushort4 o;
    float q;
    q = fminf(fmaxf(rintf(v[i].x / scale), -127.0f), 127.0f); o.x = f32_bits_bf16(q);
    q = fminf(fmaxf(rintf(v[i].y / scale), -127.0f), 127.0f); o.y = f32_bits_bf16(q);
    q = fminf(fmaxf(rintf(v[i].z / scale), -127.0f), 127.0f); o.z = f32_bits_bf16(q);
    q = fminf(fmaxf(rintf(v[i].w / scale), -127.0f), 127.0f); o.w = f32_bits_bf16(q);
    o4[t + (i << 8)] = o;
  }
}

// ---------------------------------------------------------------------------
// BT GEMM: C[m,n] = (sum_k A[m,k]*B[n,k]) * sA[m] * sB[n]
// A: [Mc,K] bf16 q, B: [N,K] bf16 q. 128x128 tile, BK=64, 4 waves (2x2),
// 16x16x32 bf16 MFMA, global_load_lds(16B) staging, both-sides XOR swizzle.
// DUAL: two B share A staging; epilogue writes silu(g)*u fp32.
// ---------------------------------------------------------------------------
template<bool DUAL>
__global__ __launch_bounds__(256, 2)
void gemm_bt_kernel(const unsigned short* __restrict__ A,
                    const unsigned short* __restrict__ B0,
                    const unsigned short* __restrict__ B1,
                    const float* __restrict__ sA,
                    const float* __restrict__ sB0,
                    const float* __restrict__ sB1,
                    float* __restrict__ out,
                    int N, int K) {
  extern __shared__ __align__(16) char smem[];
  char* const As  = smem;            // 128x64 bf16 = 16 KB
  char* const Bs0 = smem + 16384;
  char* const Bs1 = smem + 32768;    // DUAL only

  const int nTn = N >> 7;
  const int nwg = gridDim.x;
  const int bid = blockIdx.x;
  // XCD-aware swizzle (grids here are always multiples of 8 -> bijective)
  const int cpx = nwg >> 3;
  const int swz = (bid & 7) * cpx + (bid >> 3);
  const int tm = swz / nTn, tn = swz - tm * nTn;
  const int m0 = tm << 7, n0 = tn << 7;

  const int t = threadIdx.x;
  const int lane = t & 63;
  const int wid = t >> 6;
  const int wr = wid >> 1, wc = wid & 1;

  const floatx4 zero = {0.f, 0.f, 0.f, 0.f};
  floatx4 acc0[4][4];
  floatx4 acc1[4][4];
#pragma unroll
  for (int i = 0; i < 4; ++i)
#pragma unroll
    for (int j = 0; j < 4; ++j) {
      acc0[i][j] = zero;
      if (DUAL) acc1[i][j] = zero;
    }

  for (int k0 = 0; k0 < K; k0 += 64) {
    // 1024 16B chunks; chunk -> (row=chunk>>3, slot=chunk&7); LDS linear,
    // source column slot pre-swizzled with the same involution as the reads.
#pragma unroll
    for (int rr = 0; rr < 4; ++rr) {
      const int chunk = (rr << 8) + t;
      const int r = chunk >> 3;
      const int c8 = (chunk & 7) ^ (r & 7);
      gload_lds16(A + (size_t)(m0 + r) * K + (k0 + (c8 << 3)), As + (chunk << 4));
    }
#pragma unroll
    for (int rr = 0; rr < 4; ++rr) {
      const int chunk = (rr << 8) + t;
      const int r = chunk >> 3;
      const int c8 = (chunk & 7) ^ (r & 7);
      const size_t goff = (size_t)(n0 + r) * K + (k0 + (c8 << 3));
      gload_lds16(B0 + goff, Bs0 + (chunk << 4));
      if (DUAL) gload_lds16(B1 + goff, Bs1 + (chunk << 4));
    }
    __syncthreads();

#pragma unroll
    for (int ks = 0; ks < 2; ++ks) {
      frag8 af[4], bf0[4], bf1[4];
#pragma unroll
      for (int i = 0; i < 4; ++i) {
        const int r = (wr << 6) + (i << 4) + (lane & 15);
        const int c8 = (ks << 2) + (lane >> 4);
        af[i] = *(const frag8*)(As + r * 128 + ((c8 ^ (r & 7)) << 4));
      }
#pragma unroll
      for (int j = 0; j < 4; ++j) {
        const int r = (wc << 6) + (j << 4) + (lane & 15);
        const int c8 = (ks << 2) + (lane >> 4);
        const int off = r * 128 + ((c8 ^ (r & 7)) << 4);
        bf0[j] = *(const frag8*)(Bs0 + off);
        if (DUAL) bf1[j] = *(const frag8*)(Bs1 + off);
      }
#pragma unroll
      for (int i = 0; i < 4; ++i)
#pragma unroll
        for (int j = 0; j < 4; ++j) {
          acc0[i][j] = __builtin_amdgcn_mfma_f32_16x16x32_bf16(af[i], bf0[j], acc0[i][j], 0, 0, 0);
          if (DUAL)
            acc1[i][j] = __builtin_amdgcn_mfma_f32_16x16x32_bf16(af[i], bf1[j], acc1[i][j], 0, 0, 0);
        }
    }
    __syncthreads();
  }

  // Epilogue. C/D layout: col = lane&15, row = (lane>>4)*4 + q  [m89/m91].
  float sb0c[4], sb1c[4];
#pragma unroll
  for (int j = 0; j < 4; ++j) {
    const int col = n0 + (wc << 6) + (j << 4) + (lane & 15);
    sb0c[j] = sB0[col];
    if (DUAL) sb1c[j] = sB1[col];
  }
#pragma unroll
  for (int i = 0; i < 4; ++i) {
#pragma unroll
    for (int q = 0; q < 4; ++q) {
      const int row = m0 + (wr << 6) + (i << 4) + ((lane >> 4) << 2) + q;
      const float sa = sA[row];
      float* op = out + (size_t)row * N + n0 + (wc << 6) + (lane & 15);
#pragma unroll
      for (int j = 0; j < 4; ++j) {
        const float g = acc0[i][j][q] * sa * sb0c[j];
        if (DUAL) {
          const float u = acc1[i][j][q] * sa * sb1c[j];
          op[j << 4] = g / (1.0f + expf(-g)) * u;   // silu(g) * u
        } else {
          op[j << 4] = g;
        }
      }
    }
  }
}

// ---------------------------------------------------------------------------
extern "C" void kernel_launch(void* const* d_in, const int* in_sizes, int n_in,
                              void* d_out, int out_size, void* d_ws, size_t ws_size,
                              hipStream_t stream) {
  const float* x  = (const float*)d_in[0];   // [4,2048,2048]
  const float* wg = (const float*)d_in[1];   // [6144,2048]
  const float* wu = (const float*)d_in[2];   // [6144,2048]
  const float* wd = (const float*)d_in[3];   // [2048,6144]
  float* out = (float*)d_out;                // [4,2048,2048] fp32

  const int M = 8192;   // B*S
  const int H = 2048;
  const int I = 6144;

  // ---- fixed workspace region (~104.2 MiB) ----
  char* ws = (char*)d_ws;
  unsigned short* xq  = (unsigned short*)(ws);                 // M*H*2 = 33,554,432
  unsigned short* wgq = (unsigned short*)(ws + 33554432);      // I*H*2 = 25,165,824
  unsigned short* wuq = (unsigned short*)(ws + 58720256);      // 25,165,824
  unsigned short* wdq = (unsigned short*)(ws + 83886080);      // 25,165,824
  float* sx  = (float*)(ws + 109051904);                       // M*4
  float* swg = (float*)(ws + 109084672);                       // I*4
  float* swu = (float*)(ws + 109109248);                       // I*4
  float* swd = (float*)(ws + 109133824);                       // H*4
  float* sh  = (float*)(ws + 109142016);                       // M*4
  const size_t chunk_base = 109174784;                         // 256-aligned

  // ---- adaptive M-chunking so h (fp32) + hq (bf16) fit in remaining ws ----
  // per-row cost: I*4 (h) + I*2 (hq) = 36,864 B
  size_t avail = (ws_size > chunk_base) ? (ws_size - chunk_base) : 0;
  long long c = (long long)(avail / ((size_t)I * 6));
  int CHUNK = (int)((c / 128) * 128);
  if (CHUNK > M) CHUNK = M;
  if (CHUNK < 128) CHUNK = 128;   // below this ws is simply too small
  float* h = (float*)(ws + chunk_base);
  unsigned short* hq = (unsigned short*)(ws + chunk_base + (size_t)CHUNK * I * 4);

  // 1) fake-quant activations and weights (q exact in bf16 + fp32 scales)
  quant_rows_kernel<2><<<M, 256, 0, stream>>>(x,  xq,  sx,  H);
  quant_rows_kernel<2><<<I, 256, 0, stream>>>(wg, wgq, swg, H);
  quant_rows_kernel<2><<<I, 256, 0, stream>>>(wu, wuq, swu, H);
  quant_rows_kernel<6><<<H, 256, 0, stream>>>(wd, wdq, swd, I);

  // 2) per M-chunk: fused gate+up GEMM -> h, quantize h, down GEMM -> out
  for (int m0 = 0; m0 < M; m0 += CHUNK) {
    const int Mc = (M - m0 < CHUNK) ? (M - m0) : CHUNK;
    gemm_bt_kernel<true><<<dim3((Mc / 128) * (I / 128)), 256, 49152, stream>>>(
        xq + (size_t)m0 * H, wgq, wuq, sx + m0, swg, swu, h, I, H);
    quant_rows_kernel<6><<<Mc, 256, 0, stream>>>(h, hq, sh + m0, I);
    gemm_bt_kernel<false><<<dim3((Mc / 128) * (H / 128)), 256, 32768, stream>>>(
        hq, wdq, nullptr, sh + m0, swd, nullptr, out + (size_t)m0 * H, H, I);
  }
}

// Round 9
// 709.538 us; speedup vs baseline: 1.4225x; 1.4225x over previous
//
#include <hip/hip_runtime.h>
#include <hip/hip_bf16.h>
#include <math.h>

typedef __attribute__((ext_vector_type(4))) int intx4;    // 16 i8 (4 VGPR) / i32x4 acc

__device__ __forceinline__ void gload_lds16(const void* g, void* l) {
  __builtin_amdgcn_global_load_lds((__attribute__((address_space(1))) void*)g,
                                   (__attribute__((address_space(3))) void*)l,
                                   16, 0, 0);
}

__device__ __forceinline__ int pack4_i8(float a, float b, float c, float d) {
  return ((int)a & 255) | (((int)b & 255) << 8) | (((int)c & 255) << 16) | (((int)d & 255) << 24);
}

// ---------------------------------------------------------------------------
// Per-row symmetric int8 fake-quant: fp32 [rows, C] -> packed i8 + fp32 scale.
// C = NITER * 1024, 256 threads/block, one block per row, fully unrolled.
// ---------------------------------------------------------------------------
template<int NITER>
__global__ void quant_rows_i8_kernel(const float* __restrict__ src,
                                     signed char* __restrict__ dst,
                                     float* __restrict__ scales,
                                     int C) {
  const int row = blockIdx.x;
  const int t = threadIdx.x;
  const float4* s4 = (const float4*)(src + (size_t)row * C);
  float4 v[NITER];
  float amax = 0.0f;
#pragma unroll
  for (int i = 0; i < NITER; ++i) {
    v[i] = s4[t + (i << 8)];
    amax = fmaxf(amax, fmaxf(fmaxf(fabsf(v[i].x), fabsf(v[i].y)),
                             fmaxf(fabsf(v[i].z), fabsf(v[i].w))));
  }
#pragma unroll
  for (int off = 32; off > 0; off >>= 1)
    amax = fmaxf(amax, __shfl_xor(amax, off));
  __shared__ float red[4];
  if ((t & 63) == 0) red[t >> 6] = amax;
  __syncthreads();
  if (t == 0) {
    float m = fmaxf(fmaxf(red[0], red[1]), fmaxf(red[2], red[3]));
    float s = fmaxf(m * (1.0f / 127.0f), 1e-8f);
    red[0] = s;
    scales[row] = s;
  }
  __syncthreads();
  const float scale = red[0];
  int* o4 = (int*)(dst + (size_t)row * C);
#pragma unroll
  for (int i = 0; i < NITER; ++i) {
    const float q0 = fminf(fmaxf(rintf(v[i].x / scale), -127.0f), 127.0f);
    const float q1 = fminf(fmaxf(rintf(v[i].y / scale), -127.0f), 127.0f);
    const float q2 = fminf(fmaxf(rintf(v[i].z / scale), -127.0f), 127.0f);
    const float q3 = fminf(fmaxf(rintf(v[i].w / scale), -127.0f), 127.0f);
    o4[t + (i << 8)] = pack4_i8(q0, q1, q2, q3);
  }
}

// ---------------------------------------------------------------------------
// i8 BT GEMM: C[m,n] = (sum_k A[m,k]*B[n,k])_i32 * sA[m] * sB[n]
// A: [Mc,K] i8, B: [N,K] i8. 128x128 tile, BK=128 (i8 row = 128B, identical
// LDS geometry / XOR involution / staging math to the verified bf16 kernel),
// 4 waves (2x2), mfma_i32_16x16x64_i8, global_load_lds(16B) staging.
// DUAL: two B share A staging; epilogue writes silu(g)*u fp32.
// ---------------------------------------------------------------------------
template<bool DUAL>
__global__ __launch_bounds__(256, 2)
void gemm_i8_kernel(const signed char* __restrict__ A,
                    const signed char* __restrict__ B0,
                    const signed char* __restrict__ B1,
                    const float* __restrict__ sA,
                    const float* __restrict__ sB0,
                    const float* __restrict__ sB1,
                    float* __restrict__ out,
                    int N, int K) {
  extern __shared__ __align__(16) char smem[];
  char* const As  = smem;            // 128 rows x 128B = 16 KB
  char* const Bs0 = smem + 16384;
  char* const Bs1 = smem + 32768;    // DUAL only

  const int nTn = N >> 7;
  const int nwg = gridDim.x;
  const int bid = blockIdx.x;
  const int cpx = nwg >> 3;          // grids are multiples of 8 -> bijective
  const int swz = (bid & 7) * cpx + (bid >> 3);
  const int tm = swz / nTn, tn = swz - tm * nTn;
  const int m0 = tm << 7, n0 = tn << 7;

  const int t = threadIdx.x;
  const int lane = t & 63;
  const int wid = t >> 6;
  const int wr = wid >> 1, wc = wid & 1;

  const intx4 zero = {0, 0, 0, 0};
  intx4 acc0[4][4];
  intx4 acc1[4][4];
#pragma unroll
  for (int i = 0; i < 4; ++i)
#pragma unroll
    for (int j = 0; j < 4; ++j) {
      acc0[i][j] = zero;
      if (DUAL) acc1[i][j] = zero;
    }

  for (int k0 = 0; k0 < K; k0 += 128) {
    // 1024 16B chunks per tile; chunk -> (row=chunk>>3, slot=chunk&7);
    // LDS linear (gload_lds requirement), source slot pre-swizzled (rule #21).
#pragma unroll
    for (int rr = 0; rr < 4; ++rr) {
      const int chunk = (rr << 8) + t;
      const int r = chunk >> 3;
      const int c8 = (chunk & 7) ^ (r & 7);
      gload_lds16(A + (size_t)(m0 + r) * K + (k0 + (c8 << 4)), As + (chunk << 4));
    }
#pragma unroll
    for (int rr = 0; rr < 4; ++rr) {
      const int chunk = (rr << 8) + t;
      const int r = chunk >> 3;
      const int c8 = (chunk & 7) ^ (r & 7);
      const size_t goff = (size_t)(n0 + r) * K + (k0 + (c8 << 4));
      gload_lds16(B0 + goff, Bs0 + (chunk << 4));
      if (DUAL) gload_lds16(B1 + goff, Bs1 + (chunk << 4));
    }
    __syncthreads();

#pragma unroll
    for (int ks = 0; ks < 2; ++ks) {   // two K=64 MFMA sub-steps per 128-K tile
      intx4 af[4], bf0[4], bf1[4];
#pragma unroll
      for (int i = 0; i < 4; ++i) {
        const int r = (wr << 6) + (i << 4) + (lane & 15);
        const int c8 = (ks << 2) + (lane >> 4);   // 16 consecutive i8 per lane
        af[i] = *(const intx4*)(As + r * 128 + ((c8 ^ (r & 7)) << 4));
      }
#pragma unroll
      for (int j = 0; j < 4; ++j) {
        const int r = (wc << 6) + (j << 4) + (lane & 15);
        const int c8 = (ks << 2) + (lane >> 4);
        const int off = r * 128 + ((c8 ^ (r & 7)) << 4);
        bf0[j] = *(const intx4*)(Bs0 + off);
        if (DUAL) bf1[j] = *(const intx4*)(Bs1 + off);
      }
#pragma unroll
      for (int i = 0; i < 4; ++i)
#pragma unroll
        for (int j = 0; j < 4; ++j) {
          acc0[i][j] = __builtin_amdgcn_mfma_i32_16x16x64_i8(af[i], bf0[j], acc0[i][j], 0, 0, 0);
          if (DUAL)
            acc1[i][j] = __builtin_amdgcn_mfma_i32_16x16x64_i8(af[i], bf1[j], acc1[i][j], 0, 0, 0);
        }
    }
    __syncthreads();
  }

  // Epilogue. C/D layout: col = lane&15, row = (lane>>4)*4 + q (shape-determined,
  // dtype-independent per m121-m128).
  float sb0c[4], sb1c[4];
#pragma unroll
  for (int j = 0; j < 4; ++j) {
    const int col = n0 + (wc << 6) + (j << 4) + (lane & 15);
    sb0c[j] = sB0[col];
    if (DUAL) sb1c[j] = sB1[col];
  }
#pragma unroll
  for (int i = 0; i < 4; ++i) {
#pragma unroll
    for (int q = 0; q < 4; ++q) {
      const int row = m0 + (wr << 6) + (i << 4) + ((lane >> 4) << 2) + q;
      const float sa = sA[row];
      float* op = out + (size_t)row * N + n0 + (wc << 6) + (lane & 15);
#pragma unroll
      for (int j = 0; j < 4; ++j) {
        const float g = (float)acc0[i][j][q] * sa * sb0c[j];
        if (DUAL) {
          const float u = (float)acc1[i][j][q] * sa * sb1c[j];
          op[j << 4] = g / (1.0f + expf(-g)) * u;   // silu(g) * u
        } else {
          op[j << 4] = g;
        }
      }
    }
  }
}

// ---------------------------------------------------------------------------
extern "C" void kernel_launch(void* const* d_in, const int* in_sizes, int n_in,
                              void* d_out, int out_size, void* d_ws, size_t ws_size,
                              hipStream_t stream) {
  const float* x  = (const float*)d_in[0];   // [4,2048,2048]
  const float* wg = (const float*)d_in[1];   // [6144,2048]
  const float* wu = (const float*)d_in[2];   // [6144,2048]
  const float* wd = (const float*)d_in[3];   // [2048,6144]
  float* out = (float*)d_out;                // [4,2048,2048] fp32

  const int M = 8192;   // B*S
  const int H = 2048;
  const int I = 6144;

  // ---- fixed workspace region (~52.1 MiB with i8 operands) ----
  char* ws = (char*)d_ws;
  signed char* xq  = (signed char*)(ws);                  // M*H   = 16,777,216
  signed char* wgq = (signed char*)(ws + 16777216);       // I*H   = 12,582,912
  signed char* wuq = (signed char*)(ws + 29360128);       // 12,582,912
  signed char* wdq = (signed char*)(ws + 41943040);       // 12,582,912
  float* sx  = (float*)(ws + 54525952);                   // M*4
  float* swg = (float*)(ws + 54558720);                   // I*4
  float* swu = (float*)(ws + 54583296);                   // I*4
  float* swd = (float*)(ws + 54607872);                   // H*4
  float* sh  = (float*)(ws + 54616064);                   // M*4
  const size_t chunk_base = 54648832;                     // 256-aligned

  // ---- adaptive M-chunking: per-row cost = I*4 (h fp32) + I*1 (hq i8) ----
  size_t avail = (ws_size > chunk_base) ? (ws_size - chunk_base) : 0;
  long long c = (long long)(avail / ((size_t)I * 5));
  int CHUNK = (int)((c / 128) * 128);
  if (CHUNK > M) CHUNK = M;
  if (CHUNK < 128) CHUNK = 128;
  float* h = (float*)(ws + chunk_base);
  signed char* hq = (signed char*)(ws + chunk_base + (size_t)CHUNK * I * 4);

  // 1) fake-quant activations and weights -> i8 + fp32 scales
  quant_rows_i8_kernel<2><<<M, 256, 0, stream>>>(x,  xq,  sx,  H);
  quant_rows_i8_kernel<2><<<I, 256, 0, stream>>>(wg, wgq, swg, H);
  quant_rows_i8_kernel<2><<<I, 256, 0, stream>>>(wu, wuq, swu, H);
  quant_rows_i8_kernel<6><<<H, 256, 0, stream>>>(wd, wdq, swd, I);

  // 2) per M-chunk: fused gate+up i8 GEMM -> h (fp32), quantize h, down GEMM
  for (int m0 = 0; m0 < M; m0 += CHUNK) {
    const int Mc = (M - m0 < CHUNK) ? (M - m0) : CHUNK;
    gemm_i8_kernel<true><<<dim3((Mc / 128) * (I / 128)), 256, 49152, stream>>>(
        xq + (size_t)m0 * H, wgq, wuq, sx + m0, swg, swu, h, I, H);
    quant_rows_i8_kernel<6><<<Mc, 256, 0, stream>>>(h, hq, sh + m0, I);
    gemm_i8_kernel<false><<<dim3((Mc / 128) * (H / 128)), 256, 32768, stream>>>(
        hq, wdq, nullptr, sh + m0, swd, nullptr, out + (size_t)m0 * H, H, I);
  }
}